// Round 8
// baseline (440.023 us; speedup 1.0000x reference)
//
#include <hip/hip_runtime.h>

// Problem constants (fixed by setup_inputs)
#define S_LEN 8192
#define HID   1024
#define NH    16
#define NKV   8
#define HD    128
#define LSEG  1024
// ws layout (halves): hid16[8388608] | wqkv[4194304] | wo16[2097152] |
//                     q16[16777216] | k16[8388608] | v16T[8388608] | ao16[16777216]

typedef float  f4  __attribute__((ext_vector_type(4)));
typedef _Float16 h4 __attribute__((ext_vector_type(4)));
typedef _Float16 h8 __attribute__((ext_vector_type(8)));

__device__ __forceinline__ void gl_lds16(const void* g, void* l) {
  __builtin_amdgcn_global_load_lds((const __attribute__((address_space(1))) void*)g,
                                   (__attribute__((address_space(3))) void*)l, 16, 0, 0);
}

// ---- pure-VALU 16-lane reductions via DPP (no ds_swizzle) ----
template <int CTRL>
__device__ __forceinline__ float dppf(float v) {
  return __builtin_bit_cast(float,
      __builtin_amdgcn_mov_dpp(__builtin_bit_cast(int, v), CTRL, 0xF, 0xF, true));
}
__device__ __forceinline__ float red16_max(float x) {
  x = fmaxf(x, dppf<0xB1>(x));   // quad_perm [1,0,3,2]  (xor 1)
  x = fmaxf(x, dppf<0x4E>(x));   // quad_perm [2,3,0,1]  (xor 2)
  x = fmaxf(x, dppf<0x141>(x));  // row_half_mirror      (combine quads in 8)
  x = fmaxf(x, dppf<0x140>(x));  // row_mirror           (combine 8s in 16)
  return x;
}
__device__ __forceinline__ float red16_sum(float x) {
  x += dppf<0xB1>(x);
  x += dppf<0x4E>(x);
  x += dppf<0x141>(x);
  x += dppf<0x140>(x);
  return x;
}

// ---------------- fp32 -> fp16 conversion (all operands) ----------------
__global__ void convert_kernel(const float* __restrict__ hid, const float* __restrict__ wq,
                               const float* __restrict__ wk, const float* __restrict__ wv,
                               const float* __restrict__ wo,
                               _Float16* __restrict__ hid16, _Float16* __restrict__ wqkv,
                               _Float16* __restrict__ wo16) {
  const int total4 = 3670016;  // 14,680,064 / 4
  for (int i = blockIdx.x * blockDim.x + threadIdx.x; i < total4; i += gridDim.x * blockDim.x) {
    int i4 = i * 4;
    const float* src; _Float16* dst;
    if      (i4 <  8388608) { src = hid + i4;              dst = hid16 + i4; }
    else if (i4 < 10485760) { src = wq + (i4 -  8388608);  dst = wqkv + (i4 - 8388608); }
    else if (i4 < 11534336) { src = wk + (i4 - 10485760);  dst = wqkv + 2097152 + (i4 - 10485760); }
    else if (i4 < 12582912) { src = wv + (i4 - 11534336);  dst = wqkv + 3145728 + (i4 - 11534336); }
    else                    { src = wo + (i4 - 12582912);  dst = wo16 + (i4 - 12582912); }
    f4 x = *(const f4*)src;
    h4 y; y[0]=(_Float16)x[0]; y[1]=(_Float16)x[1]; y[2]=(_Float16)x[2]; y[3]=(_Float16)x[3];
    *(h4*)dst = y;
  }
}

// ---------------- 128x128-tile f16 MFMA GEMM (C = A @ B^T), BK=64 ----------------
// XCD-chunked block swizzle (T1): XCD k gets a contiguous range of tile ids so
// its A-panels stay L2-resident.
template <int FUSED>
__global__ __launch_bounds__(256, 3)
void gemm_kernel(const _Float16* __restrict__ A, const _Float16* __restrict__ B,
                 float* __restrict__ Cout, int K, int N,
                 const float* __restrict__ cosp, const float* __restrict__ sinp,
                 const float* __restrict__ qnw, const float* __restrict__ knw,
                 _Float16* __restrict__ q16, _Float16* __restrict__ k16,
                 _Float16* __restrict__ v16T) {
  __shared__ __align__(16) char smem[32768];  // As0 8K | As1 8K | Bs0 8K | Bs1 8K

  constexpr int GX  = FUSED ? 32 : 8;       // gridDim.x (compile-time)
  constexpr int NWG = FUSED ? 2048 : 512;   // total blocks; % 8 == 0 -> bijective
  const int lin = blockIdx.y * GX + blockIdx.x;            // HW dispatch order (x-fast)
  const int swz = (lin & 7) * (NWG >> 3) + (lin >> 3);     // XCD k -> contiguous chunk
  const int bx = swz & (GX - 1), by = swz / GX;

  const int tid = threadIdx.x, w = tid >> 6, ln = tid & 63;
  const int l15 = ln & 15, l4 = ln >> 4;
  const int m0 = by * 128, n0 = bx * 128;
  const int sg_row = ln >> 2, sg_cho = (ln & 3) * 8;

  f4 acc[2][8] = {};

  for (int k0 = 0; k0 < K; k0 += 64) {
    __syncthreads();
#pragma unroll
    for (int r = 0; r < 2; r++) {
      int ch = r * 4 + w;  // wave-uniform 1KB chunk id (0..7)
#pragma unroll
      for (int u = 0; u < 2; u++) {
        gl_lds16(A + (size_t)(m0 + ch * 16 + sg_row) * K + k0 + u * 32 + sg_cho,
                 smem + u * 8192 + ch * 1024);
        gl_lds16(B + (size_t)(n0 + ch * 16 + sg_row) * K + k0 + u * 32 + sg_cho,
                 smem + 16384 + u * 8192 + ch * 1024);
      }
    }
    __syncthreads();
#pragma unroll
    for (int u = 0; u < 2; u++) {
      const _Float16* As = (const _Float16*)(smem + u * 8192);
      const _Float16* Bs = (const _Float16*)(smem + 16384 + u * 8192);
      h8 af[2], bf[8];
#pragma unroll
      for (int mt = 0; mt < 2; mt++) af[mt] = *(const h8*)(As + (w * 32 + mt * 16 + l15) * 32 + l4 * 8);
#pragma unroll
      for (int nt = 0; nt < 8; nt++) bf[nt] = *(const h8*)(Bs + (nt * 16 + l15) * 32 + l4 * 8);
#pragma unroll
      for (int mt = 0; mt < 2; mt++)
#pragma unroll
        for (int nt = 0; nt < 8; nt++)
          acc[mt][nt] = __builtin_amdgcn_mfma_f32_16x16x32_f16(af[mt], bf[nt], acc[mt][nt], 0, 0, 0);
    }
  }

  if (!FUSED) {
    // plain fp32 epilogue (output projection)
#pragma unroll
    for (int mt = 0; mt < 2; mt++)
#pragma unroll
      for (int rg = 0; rg < 4; rg++) {
        int row = m0 + w * 32 + mt * 16 + l4 * 4 + rg;
#pragma unroll
        for (int nt = 0; nt < 8; nt++)
          Cout[(size_t)row * N + n0 + nt * 16 + l15] = acc[mt][nt][rg];
      }
    return;
  } else {
    // fused RMSNorm + multimodal RoPE epilogue -> q16/k16 ([h][s][d]) and v16T ([hkv][d][s])
    const int head = bx;  // 0..15 q, 16..23 k, 24..31 v
    if (head < 24) {
      const float* nw = (head < 16) ? qnw : knw;
      // q: fold D^-0.5 * log2(e) (attn softmax runs in exp2 domain)
      const float hs = (head < 16) ? 0.12751734f : 1.0f;
      _Float16* base = (head < 16) ? q16 + (size_t)head * S_LEN * HD
                                   : k16 + (size_t)(head - 16) * S_LEN * HD;
      float nwv[8];
#pragma unroll
      for (int nt = 0; nt < 8; nt++) nwv[nt] = nw[nt * 16 + l15];
#pragma unroll
      for (int mt = 0; mt < 2; mt++)
#pragma unroll
        for (int rg = 0; rg < 4; rg++) {
          const int row = m0 + w * 32 + mt * 16 + l4 * 4 + rg;  // global s
          float ss = 0.f;
#pragma unroll
          for (int nt = 0; nt < 8; nt++) ss += acc[mt][nt][rg] * acc[mt][nt][rg];
          ss = red16_sum(ss);
          const float sc = rsqrtf(ss * 0.0078125f + 1e-6f);
#pragma unroll
          for (int nt = 0; nt < 8; nt++) {
            const int c = nt * 16 + l15;
            const int str = (nt >= 4) ? 1048576 : 0;  // RoPE stream per half-dim
            float x  = acc[mt][nt][rg] * sc * nwv[nt];
            float xp = acc[mt][nt ^ 4][rg] * sc * nwv[nt ^ 4];
            float ce = cosp[str + row * HD + c];
            float se = sinp[str + row * HD + c];
            float rot = (nt >= 4) ? xp : -xp;
            base[(size_t)row * HD + c] = (_Float16)((x * ce + rot * se) * hs);
          }
        }
    } else {
      // V: h4 stores -- rg=0..3 are 4 consecutive s-rows for fixed d -> 8B contiguous
      _Float16* vb = v16T + (size_t)(head - 24) * S_LEN * HD;  // [d][s]
#pragma unroll
      for (int mt = 0; mt < 2; mt++)
#pragma unroll
        for (int nt = 0; nt < 8; nt++) {
          h4 hv;
#pragma unroll
          for (int rg = 0; rg < 4; rg++) hv[rg] = (_Float16)acc[mt][nt][rg];
          *(h4*)&vb[(size_t)(nt * 16 + l15) * S_LEN + m0 + w * 32 + mt * 16 + l4 * 4] = hv;
        }
    }
  }
}

// ---------------- flash attention, R13 = R12 resubmitted (infra failure, no data) ----------------
// R11 post-mortem: doubling occupancy (40%) changed nothing -> latency is
// covered at 2 waves/SIMD; the limiter is the LDS/VALU instruction stream.
// R10's padded strides (132/68) force every fragment load to be 2x ds_read_b64
// (ld8u) + fix-ups. R12 switches all tiles to LINEAR strides + XOR swizzle
// (idx ^ ((row&7)<<3), the R7-verified formula): every fragment load becomes
// ONE ds_read_b128, conflict-free (rows 0-7 cover all 32 banks; 8-15 alias
// 2-way = free). Staging writes become single uint4 stores. LDS 68608->65536.
// Geometry/barriers/defer-max/setprio/XCD decode: R10 verbatim (4 waves,
// 32 q-rows/wave, 3 barriers/iter).
__global__ __launch_bounds__(256, 2)
void attn_kernel(const _Float16* __restrict__ q16, const _Float16* __restrict__ k16,
                 const _Float16* __restrict__ vT, _Float16* __restrict__ ao16) {
  const int bid = blockIdx.x;
  const int xcd = bid & 7, slot = bid >> 3;   // 8 XCDs x 128 slots (1024 % 8 == 0)
  const int grp = xcd * 8 + (slot >> 4);      // 0..63 = (g, hkv) group, 8 groups/XCD
  const int mem = slot & 15;                  // 16 members share this group's K/V (512KB)
  const int g = grp >> 3, hkv = grp & 7;
  const int tq = mem & 7, h = hkv * 2 + (mem >> 3);

  const int tid = threadIdx.x, w = tid >> 6, ln = tid & 63;
  const int l15 = ln & 15, l4 = ln >> 4;
  const int fsw = (l15 & 7) << 3;  // fragment-read swizzle (lane-constant)

  __shared__ __align__(16) _Float16 Qs[128 * 128];  // [q][d] swz, 32768 B
  __shared__ __align__(16) _Float16 KP[64 * 128];   // K [l][d] swz / P [q][l] swz, 16384 B
  __shared__ __align__(16) _Float16 Vt[128 * 64];   // [d][l] swz, 16384 B

  // stage Q tile (128 x 128) swizzled, uint4 stores
  const _Float16* qsrc = q16 + ((size_t)h * S_LEN + g * LSEG + tq * 128) * HD;
#pragma unroll
  for (int i = 0; i < 8; i++) {
    int c = tid + 256 * i, row = c >> 4, o = c & 15;
    uint4 v = *(const uint4*)(qsrc + row * HD + o * 8);
    *(uint4*)&Qs[(row * 128 + o * 8) ^ ((row & 7) << 3)] = v;
  }

  f4 O[2][8] = {};
  float mr[2][4], lr[2][4];
#pragma unroll
  for (int mt = 0; mt < 2; mt++)
#pragma unroll
    for (int rg = 0; rg < 4; rg++) { mr[mt][rg] = -1e30f; lr[mt][rg] = 0.f; }

  const size_t kbase = ((size_t)hkv * S_LEN + g * LSEG) * HD;
  const size_t vbase = (size_t)hkv * S_LEN * HD + (size_t)g * LSEG;

  // per-thread staging coordinates (fixed)
  const int krow = tid >> 4, ko = tid & 15;   // + 16*i rows
  const int vd   = tid >> 3, vo = tid & 7;    // + 32*i d-rows

  // ---- preload tile 0 into registers, then LDS (swizzled uint4 stores) ----
  uint4 kr[4], vr[4];
#pragma unroll
  for (int i = 0; i < 4; i++) {
    kr[i] = *(const uint4*)(k16 + kbase + (size_t)(krow + 16 * i) * HD + ko * 8);
    vr[i] = *(const uint4*)(vT + vbase + (size_t)(vd + 32 * i) * S_LEN + vo * 8);
  }
#pragma unroll
  for (int i = 0; i < 4; i++) {
    int row = krow + 16 * i;
    *(uint4*)&KP[(row * 128 + ko * 8) ^ ((row & 7) << 3)] = kr[i];
    int d = vd + 32 * i;
    *(uint4*)&Vt[(d * 64 + vo * 8) ^ ((d & 7) << 3)] = vr[i];
  }

  for (int j = 0; j < 16; j++) {
    __syncthreads();  // staged tile j visible (and Q at j=0)

    // ---- issue prefetch loads for tile j+1 (wrap: redundant reload of 0) ----
    const int jn = (j + 1) & 15;
#pragma unroll
    for (int i = 0; i < 4; i++) {
      kr[i] = *(const uint4*)(k16 + kbase + (size_t)(jn * 64 + krow + 16 * i) * HD + ko * 8);
      vr[i] = *(const uint4*)(vT + vbase + (size_t)(vd + 32 * i) * S_LEN + jn * 64 + vo * 8);
    }

    // S = Q K^T  (wave w owns q-rows 32w..32w+31, all 64 l-cols; all b128)
    f4 s[2][4] = {};
    __builtin_amdgcn_s_setprio(1);
#pragma unroll
    for (int kk = 0; kk < 4; kk++) {
      h8 a0 = *(const h8*)&Qs[((w * 32 + l15) * 128 + kk * 32 + l4 * 8) ^ fsw];
      h8 a1 = *(const h8*)&Qs[((w * 32 + 16 + l15) * 128 + kk * 32 + l4 * 8) ^ fsw];
#pragma unroll
      for (int nt = 0; nt < 4; nt++) {
        h8 b = *(const h8*)&KP[((nt * 16 + l15) * 128 + kk * 32 + l4 * 8) ^ fsw];
        s[0][nt] = __builtin_amdgcn_mfma_f32_16x16x32_f16(a0, b, s[0][nt], 0, 0, 0);
        s[1][nt] = __builtin_amdgcn_mfma_f32_16x16x32_f16(a1, b, s[1][nt], 0, 0, 0);
      }
    }
    __builtin_amdgcn_s_setprio(0);

    // ---- online softmax, exp2 domain, with defer-max (T13) ----
    float mx[2][4];
    bool nd = false;
#pragma unroll
    for (int mt = 0; mt < 2; mt++)
#pragma unroll
      for (int rg = 0; rg < 4; rg++) {
        float m = fmaxf(fmaxf(s[mt][0][rg], s[mt][1][rg]), fmaxf(s[mt][2][rg], s[mt][3][rg]));
        m = red16_max(m);
        mx[mt][rg] = m;
        nd = nd || (m > mr[mt][rg] + 8.f);
      }
    const bool needr = __any((int)nd) != 0;  // wave-uniform
    float al[2][4];
    if (needr) {
#pragma unroll
      for (int mt = 0; mt < 2; mt++)
#pragma unroll
        for (int rg = 0; rg < 4; rg++) {
          float mnew = fmaxf(mr[mt][rg], mx[mt][rg]);
          al[mt][rg] = exp2f(mr[mt][rg] - mnew);
          mr[mt][rg] = mnew;
        }
    }
#pragma unroll
    for (int mt = 0; mt < 2; mt++)
#pragma unroll
      for (int rg = 0; rg < 4; rg++) {
        float rs = 0.f;
#pragma unroll
        for (int nt = 0; nt < 4; nt++) {
          float p = exp2f(s[mt][nt][rg] - mr[mt][rg]);
          s[mt][nt][rg] = p;
          rs += p;
        }
        rs = red16_sum(rs);
        if (needr) lr[mt][rg] = lr[mt][rg] * al[mt][rg] + rs;
        else       lr[mt][rg] += rs;
      }

    __syncthreads();  // all waves done reading KP as K -> safe to write P
    // write P ([q][l] swz; wave-local rows [32w,32w+32))
#pragma unroll
    for (int mt = 0; mt < 2; mt++)
#pragma unroll
      for (int nt = 0; nt < 4; nt++)
#pragma unroll
        for (int rg = 0; rg < 4; rg++) {
          int q = w * 32 + mt * 16 + l4 * 4 + rg;
          KP[(q * 64 + nt * 16 + l15) ^ ((q & 7) << 3)] = (_Float16)s[mt][nt][rg];
        }
    // rescale O while P-write settles (skipped most iters via defer-max)
    if (needr) {
#pragma unroll
      for (int mt = 0; mt < 2; mt++)
#pragma unroll
        for (int d8 = 0; d8 < 8; d8++)
#pragma unroll
          for (int rg = 0; rg < 4; rg++) O[mt][d8][rg] *= al[mt][rg];
    }
    // (no barrier: PV reads only this wave's own P rows; lgkmcnt orders RAW)

    // O += P @ V   (A = own P rows, B = Vt; all b128)
    __builtin_amdgcn_s_setprio(1);
#pragma unroll
    for (int kk = 0; kk < 2; kk++) {
      h8 a0 = *(const h8*)&KP[((w * 32 + l15) * 64 + kk * 32 + l4 * 8) ^ fsw];
      h8 a1 = *(const h8*)&KP[((w * 32 + 16 + l15) * 64 + kk * 32 + l4 * 8) ^ fsw];
#pragma unroll
      for (int d8 = 0; d8 < 8; d8++) {
        h8 b = *(const h8*)&Vt[((d8 * 16 + l15) * 64 + kk * 32 + l4 * 8) ^ fsw];
        O[0][d8] = __builtin_amdgcn_mfma_f32_16x16x32_f16(a0, b, O[0][d8], 0, 0, 0);
        O[1][d8] = __builtin_amdgcn_mfma_f32_16x16x32_f16(a1, b, O[1][d8], 0, 0, 0);
      }
    }
    __builtin_amdgcn_s_setprio(0);

    __syncthreads();  // all waves done reading KP (as P) and Vt -> safe to restage
    // ---- write prefetched tile j+1 to LDS (swizzled uint4) ----
#pragma unroll
    for (int i = 0; i < 4; i++) {
      int row = krow + 16 * i;
      *(uint4*)&KP[(row * 128 + ko * 8) ^ ((row & 7) << 3)] = kr[i];
      int d = vd + 32 * i;
      *(uint4*)&Vt[(d * 64 + vo * 8) ^ ((d & 7) << 3)] = vr[i];
    }
  }

  // epilogue: O / l -> ao16 [s][h*128+d]
  const size_t obase = (size_t)(g * LSEG + tq * 128);
#pragma unroll
  for (int mt = 0; mt < 2; mt++)
#pragma unroll
    for (int rg = 0; rg < 4; rg++) {
      float inv = 1.f / lr[mt][rg];
#pragma unroll
      for (int d8 = 0; d8 < 8; d8++)
        ao16[(obase + w * 32 + mt * 16 + l4 * 4 + rg) * 2048 + h * HD + d8 * 16 + l15] =
            (_Float16)(O[mt][d8][rg] * inv);
    }
}

extern "C" void kernel_launch(void* const* d_in, const int* in_sizes, int n_in,
                              void* d_out, int out_size, void* d_ws, size_t ws_size,
                              hipStream_t stream) {
  const float* hid  = (const float*)d_in[0];
  // d_in[1] = cu_seqlens: static equal segments, unused
  const float* cosp = (const float*)d_in[2];
  const float* sinp = (const float*)d_in[3];
  const float* wq   = (const float*)d_in[4];
  const float* wk   = (const float*)d_in[5];
  const float* wv   = (const float*)d_in[6];
  const float* wo   = (const float*)d_in[7];
  const float* qnw  = (const float*)d_in[8];
  const float* knw  = (const float*)d_in[9];
  float* out = (float*)d_out;

  _Float16* hid16 = (_Float16*)d_ws;
  _Float16* wqkv  = hid16 + 8388608;
  _Float16* wo16  = wqkv + 4194304;
  _Float16* q16   = wo16 + 2097152;
  _Float16* k16   = q16 + 16777216;
  _Float16* v16T  = k16 + 8388608;
  _Float16* ao16  = v16T + 8388608;

  convert_kernel<<<dim3(1024), dim3(256), 0, stream>>>(hid, wq, wk, wv, wo, hid16, wqkv, wo16);
  gemm_kernel<1><<<dim3(32, 64), dim3(256), 0, stream>>>(hid16, wqkv, nullptr, 1024, 4096,
                                                         cosp, sinp, qnw, knw, q16, k16, v16T);
  attn_kernel<<<dim3(1024), dim3(256), 0, stream>>>(q16, k16, v16T, ao16);
  gemm_kernel<0><<<dim3(8, 64), dim3(256), 0, stream>>>(ao16, wo16, out, 2048, 1024,
                                                        nullptr, nullptr, nullptr, nullptr,
                                                        nullptr, nullptr, nullptr);
}

// Round 9
// 389.643 us; speedup vs baseline: 1.1293x; 1.1293x over previous
//
#include <hip/hip_runtime.h>

// Problem constants (fixed by setup_inputs)
#define S_LEN 8192
#define HID   1024
#define NH    16
#define NKV   8
#define HD    128
#define LSEG  1024
// ws layout (halves): hid16[8388608] | wqkv[4194304] | wo16[2097152] |
//                     q16[16777216] | k16[8388608] | v16T[8388608] | ao16[16777216]

typedef float  f4  __attribute__((ext_vector_type(4)));
typedef _Float16 h4 __attribute__((ext_vector_type(4)));
typedef _Float16 h8 __attribute__((ext_vector_type(8)));

__device__ __forceinline__ void gl_lds16(const void* g, void* l) {
  __builtin_amdgcn_global_load_lds((const __attribute__((address_space(1))) void*)g,
                                   (__attribute__((address_space(3))) void*)l, 16, 0, 0);
}

__device__ __forceinline__ h8 ld8u(const _Float16* p) {  // 8B-aligned LDS load
  h4 a = *(const h4*)p;
  h4 b = *(const h4*)(p + 4);
  return __builtin_shufflevector(a, b, 0, 1, 2, 3, 4, 5, 6, 7);
}

// ---- pure-VALU 16-lane reductions via DPP (no ds_swizzle) ----
template <int CTRL>
__device__ __forceinline__ float dppf(float v) {
  return __builtin_bit_cast(float,
      __builtin_amdgcn_mov_dpp(__builtin_bit_cast(int, v), CTRL, 0xF, 0xF, true));
}
__device__ __forceinline__ float red16_max(float x) {
  x = fmaxf(x, dppf<0xB1>(x));   // quad_perm [1,0,3,2]  (xor 1)
  x = fmaxf(x, dppf<0x4E>(x));   // quad_perm [2,3,0,1]  (xor 2)
  x = fmaxf(x, dppf<0x141>(x));  // row_half_mirror      (combine quads in 8)
  x = fmaxf(x, dppf<0x140>(x));  // row_mirror           (combine 8s in 16)
  return x;
}
__device__ __forceinline__ float red16_sum(float x) {
  x += dppf<0xB1>(x);
  x += dppf<0x4E>(x);
  x += dppf<0x141>(x);
  x += dppf<0x140>(x);
  return x;
}
// broadcast from lane (l & 0x10) -- BitMode and=0x10, or=0, xor=0
__device__ __forceinline__ float bcast16(float v) {
  return __builtin_bit_cast(float,
      __builtin_amdgcn_ds_swizzle(__builtin_bit_cast(int, v), 0x0010));
}

// ---------------- fp32 -> fp16 conversion (all operands) ----------------
__global__ void convert_kernel(const float* __restrict__ hid, const float* __restrict__ wq,
                               const float* __restrict__ wk, const float* __restrict__ wv,
                               const float* __restrict__ wo,
                               _Float16* __restrict__ hid16, _Float16* __restrict__ wqkv,
                               _Float16* __restrict__ wo16) {
  const int total4 = 3670016;  // 14,680,064 / 4
  for (int i = blockIdx.x * blockDim.x + threadIdx.x; i < total4; i += gridDim.x * blockDim.x) {
    int i4 = i * 4;
    const float* src; _Float16* dst;
    if      (i4 <  8388608) { src = hid + i4;              dst = hid16 + i4; }
    else if (i4 < 10485760) { src = wq + (i4 -  8388608);  dst = wqkv + (i4 - 8388608); }
    else if (i4 < 11534336) { src = wk + (i4 - 10485760);  dst = wqkv + 2097152 + (i4 - 10485760); }
    else if (i4 < 12582912) { src = wv + (i4 - 11534336);  dst = wqkv + 3145728 + (i4 - 11534336); }
    else                    { src = wo + (i4 - 12582912);  dst = wo16 + (i4 - 12582912); }
    f4 x = *(const f4*)src;
    h4 y; y[0]=(_Float16)x[0]; y[1]=(_Float16)x[1]; y[2]=(_Float16)x[2]; y[3]=(_Float16)x[3];
    *(h4*)dst = y;
  }
}

// ---------------- 128x128-tile f16 MFMA GEMM (C = A @ B^T), BK=64 ----------------
// XCD-chunked block swizzle (T1): XCD k gets a contiguous range of tile ids so
// its A-panels stay L2-resident.
template <int FUSED>
__global__ __launch_bounds__(256, 3)
void gemm_kernel(const _Float16* __restrict__ A, const _Float16* __restrict__ B,
                 float* __restrict__ Cout, int K, int N,
                 const float* __restrict__ cosp, const float* __restrict__ sinp,
                 const float* __restrict__ qnw, const float* __restrict__ knw,
                 _Float16* __restrict__ q16, _Float16* __restrict__ k16,
                 _Float16* __restrict__ v16T) {
  __shared__ __align__(16) char smem[32768];  // As0 8K | As1 8K | Bs0 8K | Bs1 8K

  constexpr int GX  = FUSED ? 32 : 8;       // gridDim.x (compile-time)
  constexpr int NWG = FUSED ? 2048 : 512;   // total blocks; % 8 == 0 -> bijective
  const int lin = blockIdx.y * GX + blockIdx.x;            // HW dispatch order (x-fast)
  const int swz = (lin & 7) * (NWG >> 3) + (lin >> 3);     // XCD k -> contiguous chunk
  const int bx = swz & (GX - 1), by = swz / GX;

  const int tid = threadIdx.x, w = tid >> 6, ln = tid & 63;
  const int l15 = ln & 15, l4 = ln >> 4;
  const int m0 = by * 128, n0 = bx * 128;
  const int sg_row = ln >> 2, sg_cho = (ln & 3) * 8;

  f4 acc[2][8] = {};

  for (int k0 = 0; k0 < K; k0 += 64) {
    __syncthreads();
#pragma unroll
    for (int r = 0; r < 2; r++) {
      int ch = r * 4 + w;  // wave-uniform 1KB chunk id (0..7)
#pragma unroll
      for (int u = 0; u < 2; u++) {
        gl_lds16(A + (size_t)(m0 + ch * 16 + sg_row) * K + k0 + u * 32 + sg_cho,
                 smem + u * 8192 + ch * 1024);
        gl_lds16(B + (size_t)(n0 + ch * 16 + sg_row) * K + k0 + u * 32 + sg_cho,
                 smem + 16384 + u * 8192 + ch * 1024);
      }
    }
    __syncthreads();
#pragma unroll
    for (int u = 0; u < 2; u++) {
      const _Float16* As = (const _Float16*)(smem + u * 8192);
      const _Float16* Bs = (const _Float16*)(smem + 16384 + u * 8192);
      h8 af[2], bf[8];
#pragma unroll
      for (int mt = 0; mt < 2; mt++) af[mt] = *(const h8*)(As + (w * 32 + mt * 16 + l15) * 32 + l4 * 8);
#pragma unroll
      for (int nt = 0; nt < 8; nt++) bf[nt] = *(const h8*)(Bs + (nt * 16 + l15) * 32 + l4 * 8);
#pragma unroll
      for (int mt = 0; mt < 2; mt++)
#pragma unroll
        for (int nt = 0; nt < 8; nt++)
          acc[mt][nt] = __builtin_amdgcn_mfma_f32_16x16x32_f16(af[mt], bf[nt], acc[mt][nt], 0, 0, 0);
    }
  }

  if (!FUSED) {
    // plain fp32 epilogue (output projection)
#pragma unroll
    for (int mt = 0; mt < 2; mt++)
#pragma unroll
      for (int rg = 0; rg < 4; rg++) {
        int row = m0 + w * 32 + mt * 16 + l4 * 4 + rg;
#pragma unroll
        for (int nt = 0; nt < 8; nt++)
          Cout[(size_t)row * N + n0 + nt * 16 + l15] = acc[mt][nt][rg];
      }
    return;
  } else {
    // fused RMSNorm + multimodal RoPE epilogue -> q16/k16 ([h][s][d]) and v16T ([hkv][d][s])
    const int head = bx;  // 0..15 q, 16..23 k, 24..31 v
    if (head < 24) {
      const float* nw = (head < 16) ? qnw : knw;
      // q: fold D^-0.5 * log2(e) (attn softmax runs in exp2 domain)
      const float hs = (head < 16) ? 0.12751734f : 1.0f;
      _Float16* base = (head < 16) ? q16 + (size_t)head * S_LEN * HD
                                   : k16 + (size_t)(head - 16) * S_LEN * HD;
      float nwv[8];
#pragma unroll
      for (int nt = 0; nt < 8; nt++) nwv[nt] = nw[nt * 16 + l15];
#pragma unroll
      for (int mt = 0; mt < 2; mt++)
#pragma unroll
        for (int rg = 0; rg < 4; rg++) {
          const int row = m0 + w * 32 + mt * 16 + l4 * 4 + rg;  // global s
          float ss = 0.f;
#pragma unroll
          for (int nt = 0; nt < 8; nt++) ss += acc[mt][nt][rg] * acc[mt][nt][rg];
          ss = red16_sum(ss);
          const float sc = rsqrtf(ss * 0.0078125f + 1e-6f);
#pragma unroll
          for (int nt = 0; nt < 8; nt++) {
            const int c = nt * 16 + l15;
            const int str = (nt >= 4) ? 1048576 : 0;  // RoPE stream per half-dim
            float x  = acc[mt][nt][rg] * sc * nwv[nt];
            float xp = acc[mt][nt ^ 4][rg] * sc * nwv[nt ^ 4];
            float ce = cosp[str + row * HD + c];
            float se = sinp[str + row * HD + c];
            float rot = (nt >= 4) ? xp : -xp;
            base[(size_t)row * HD + c] = (_Float16)((x * ce + rot * se) * hs);
          }
        }
    } else {
      // V: h4 stores -- rg=0..3 are 4 consecutive s-rows for fixed d -> 8B contiguous
      _Float16* vb = v16T + (size_t)(head - 24) * S_LEN * HD;  // [d][s]
#pragma unroll
      for (int mt = 0; mt < 2; mt++)
#pragma unroll
        for (int nt = 0; nt < 8; nt++) {
          h4 hv;
#pragma unroll
          for (int rg = 0; rg < 4; rg++) hv[rg] = (_Float16)acc[mt][nt][rg];
          *(h4*)&vb[(size_t)(nt * 16 + l15) * S_LEN + m0 + w * 32 + mt * 16 + l4 * 4] = hv;
        }
    }
  }
}

// ---------------- flash attention, R14 = R10 + chain-free softmax ----------------
// R12/R13 post-mortem: b128+XOR-swizzle = 16.1M conflicts (6.5x worse than
// R10's padded-stride ld8u scheme) -> reverted to R10 layout wholesale.
// R14 attacks the 52% VALUBusy: both per-row DPP reduction chains removed.
//  (a) detection-only defer-max: per-lane compares + __any replace the 8
//      red16_max chains; real max computed only on the rare rescale path.
//  (b) denominator via ones-row MFMA: Vt rows 128..143 = [ones, zeros...];
//      PV's 9th d8-tile accumulates sum_l P[q][l] into O[mt][8], rescaled
//      with O automatically. Replaces 8 red16_sum chains + lr bookkeeping
//      with 4 extra MFMA/iter. Numerator/denominator now share fp16 P.
//      Epilogue: one ds_swizzle (and=0x10) broadcast recovers the sum.
// LDS 68608 -> 70784 (2 blocks/CU unchanged). VGPR ~116 (cap 256, no spill).
__global__ __launch_bounds__(256, 2)
void attn_kernel(const _Float16* __restrict__ q16, const _Float16* __restrict__ k16,
                 const _Float16* __restrict__ vT, _Float16* __restrict__ ao16) {
  const int bid = blockIdx.x;
  const int xcd = bid & 7, slot = bid >> 3;   // 8 XCDs x 128 slots (1024 % 8 == 0)
  const int grp = xcd * 8 + (slot >> 4);      // 0..63 = (g, hkv) group, 8 groups/XCD
  const int mem = slot & 15;                  // 16 members share this group's K/V (512KB)
  const int g = grp >> 3, hkv = grp & 7;
  const int tq = mem & 7, h = hkv * 2 + (mem >> 3);

  const int tid = threadIdx.x, w = tid >> 6, ln = tid & 63;
  const int l15 = ln & 15, l4 = ln >> 4;

  __shared__ _Float16 Qs[128 * 132];  // [qrow][d], stride 132 (33792 B)
  __shared__ _Float16 KP[128 * 68];   // K: [l(64)][d] stride 132 / P: [qrow][l] stride 68
  __shared__ _Float16 Vt[144 * 68];   // [d=128+16][l(64)+pad], stride 68; rows 128..143: ones/zeros

  // stage Q tile (128 x 128), stride 132
  const _Float16* qsrc = q16 + ((size_t)h * S_LEN + g * LSEG + tq * 128) * HD;
#pragma unroll
  for (int i = 0; i < 8; i++) {
    int c = tid + 256 * i, row = c >> 4, o = c & 15;
    uint4 v = *(const uint4*)(qsrc + row * HD + o * 8);
    *(uint2*)&Qs[row * 132 + o * 8]     = make_uint2(v.x, v.y);
    *(uint2*)&Qs[row * 132 + o * 8 + 4] = make_uint2(v.z, v.w);
  }
  // ones-row (d=128) + zero rows (129..143) for the denominator MFMA tile
  if (tid < 68) {
    Vt[128 * 68 + tid] = (_Float16)1.0f;
#pragma unroll
    for (int r = 129; r < 144; r++) Vt[r * 68 + tid] = (_Float16)0.0f;
  }

  f4 O[2][9] = {};   // [mt][0..7]=output tiles, [mt][8]=denominator tile
  float mr[2][4];
#pragma unroll
  for (int mt = 0; mt < 2; mt++)
#pragma unroll
    for (int rg = 0; rg < 4; rg++) mr[mt][rg] = -1e30f;

  const size_t kbase = ((size_t)hkv * S_LEN + g * LSEG) * HD;
  const size_t vbase = (size_t)hkv * S_LEN * HD + (size_t)g * LSEG;

  // per-thread staging coordinates (fixed)
  const int krow = tid >> 4, ko = tid & 15;   // + 16*i rows
  const int vd   = tid >> 3, vo = tid & 7;    // + 32*i d-rows

  // ---- preload tile 0 into registers, then LDS ----
  uint4 kr[4], vr[4];
#pragma unroll
  for (int i = 0; i < 4; i++) {
    kr[i] = *(const uint4*)(k16 + kbase + (size_t)(krow + 16 * i) * HD + ko * 8);
    vr[i] = *(const uint4*)(vT + vbase + (size_t)(vd + 32 * i) * S_LEN + vo * 8);
  }
#pragma unroll
  for (int i = 0; i < 4; i++) {
    int row = krow + 16 * i;
    *(uint2*)&KP[row * 132 + ko * 8]     = make_uint2(kr[i].x, kr[i].y);
    *(uint2*)&KP[row * 132 + ko * 8 + 4] = make_uint2(kr[i].z, kr[i].w);
    int d = vd + 32 * i;
    *(uint2*)&Vt[d * 68 + vo * 8]     = make_uint2(vr[i].x, vr[i].y);
    *(uint2*)&Vt[d * 68 + vo * 8 + 4] = make_uint2(vr[i].z, vr[i].w);
  }

  for (int j = 0; j < 16; j++) {
    __syncthreads();  // staged tile j visible (and Q, ones-rows at j=0)

    // ---- issue prefetch loads for tile j+1 (wrap: redundant reload of 0) ----
    const int jn = (j + 1) & 15;
#pragma unroll
    for (int i = 0; i < 4; i++) {
      kr[i] = *(const uint4*)(k16 + kbase + (size_t)(jn * 64 + krow + 16 * i) * HD + ko * 8);
      vr[i] = *(const uint4*)(vT + vbase + (size_t)(vd + 32 * i) * S_LEN + jn * 64 + vo * 8);
    }

    // S = Q K^T  (wave w owns q-rows 32w..32w+31, all 64 l-cols)
    f4 s[2][4] = {};
    __builtin_amdgcn_s_setprio(1);
#pragma unroll
    for (int kk = 0; kk < 4; kk++) {
      h8 a0 = ld8u(Qs + (w * 32 + l15) * 132 + kk * 32 + l4 * 8);
      h8 a1 = ld8u(Qs + (w * 32 + 16 + l15) * 132 + kk * 32 + l4 * 8);
#pragma unroll
      for (int nt = 0; nt < 4; nt++) {
        h8 b = ld8u(KP + (nt * 16 + l15) * 132 + kk * 32 + l4 * 8);
        s[0][nt] = __builtin_amdgcn_mfma_f32_16x16x32_f16(a0, b, s[0][nt], 0, 0, 0);
        s[1][nt] = __builtin_amdgcn_mfma_f32_16x16x32_f16(a1, b, s[1][nt], 0, 0, 0);
      }
    }
    __builtin_amdgcn_s_setprio(0);

    // ---- chain-free softmax: detection-only defer-max ----
    bool nd = false;
#pragma unroll
    for (int mt = 0; mt < 2; mt++)
#pragma unroll
      for (int rg = 0; rg < 4; rg++) {
        float thr = mr[mt][rg] + 8.f;
        nd = nd || (s[mt][0][rg] > thr) || (s[mt][1][rg] > thr) ||
                   (s[mt][2][rg] > thr) || (s[mt][3][rg] > thr);
      }
    const bool needr = __any((int)nd) != 0;  // wave-uniform, rare
    float al[2][4];
    if (needr) {
#pragma unroll
      for (int mt = 0; mt < 2; mt++)
#pragma unroll
        for (int rg = 0; rg < 4; rg++) {
          float m = fmaxf(fmaxf(s[mt][0][rg], s[mt][1][rg]), fmaxf(s[mt][2][rg], s[mt][3][rg]));
          m = red16_max(m);
          float mnew = fmaxf(mr[mt][rg], m);
          al[mt][rg] = exp2f(mr[mt][rg] - mnew);
          mr[mt][rg] = mnew;
        }
    }
    // P = exp2(S - mr) (no row-sum: denominator comes from the ones-row MFMA)
#pragma unroll
    for (int mt = 0; mt < 2; mt++)
#pragma unroll
      for (int rg = 0; rg < 4; rg++)
#pragma unroll
        for (int nt = 0; nt < 4; nt++)
          s[mt][nt][rg] = exp2f(s[mt][nt][rg] - mr[mt][rg]);

    __syncthreads();  // all waves done reading KP as K -> safe to write P
    // write P (C-layout -> LDS [qrow][l] stride 68; wave-local rows [32w,32w+32))
#pragma unroll
    for (int mt = 0; mt < 2; mt++)
#pragma unroll
      for (int nt = 0; nt < 4; nt++)
#pragma unroll
        for (int rg = 0; rg < 4; rg++)
          KP[(w * 32 + mt * 16 + l4 * 4 + rg) * 68 + nt * 16 + l15] = (_Float16)s[mt][nt][rg];
    // rescale O (incl. denominator tile) while P-write settles; usually skipped
    if (needr) {
#pragma unroll
      for (int mt = 0; mt < 2; mt++)
#pragma unroll
        for (int d8 = 0; d8 < 9; d8++)
#pragma unroll
          for (int rg = 0; rg < 4; rg++) O[mt][d8][rg] *= al[mt][rg];
    }
    // (no barrier: PV reads only this wave's own P rows; lgkmcnt orders RAW)

    // O += P @ V   (A = own P rows, B = Vt; d8=8 is the ones/denominator tile)
    __builtin_amdgcn_s_setprio(1);
#pragma unroll
    for (int kk = 0; kk < 2; kk++) {
      h8 a0 = ld8u(KP + (w * 32 + l15) * 68 + kk * 32 + l4 * 8);
      h8 a1 = ld8u(KP + (w * 32 + 16 + l15) * 68 + kk * 32 + l4 * 8);
#pragma unroll
      for (int d8 = 0; d8 < 9; d8++) {
        h8 b = ld8u(Vt + (d8 * 16 + l15) * 68 + kk * 32 + l4 * 8);
        O[0][d8] = __builtin_amdgcn_mfma_f32_16x16x32_f16(a0, b, O[0][d8], 0, 0, 0);
        O[1][d8] = __builtin_amdgcn_mfma_f32_16x16x32_f16(a1, b, O[1][d8], 0, 0, 0);
      }
    }
    __builtin_amdgcn_s_setprio(0);

    __syncthreads();  // all waves done reading KP (as P) and Vt -> safe to restage
    // ---- write prefetched tile j+1 to LDS (rows 0..127 only; ones rows persist) ----
#pragma unroll
    for (int i = 0; i < 4; i++) {
      int row = krow + 16 * i;
      *(uint2*)&KP[row * 132 + ko * 8]     = make_uint2(kr[i].x, kr[i].y);
      *(uint2*)&KP[row * 132 + ko * 8 + 4] = make_uint2(kr[i].z, kr[i].w);
      int d = vd + 32 * i;
      *(uint2*)&Vt[d * 68 + vo * 8]     = make_uint2(vr[i].x, vr[i].y);
      *(uint2*)&Vt[d * 68 + vo * 8 + 4] = make_uint2(vr[i].z, vr[i].w);
    }
  }

  // epilogue: O / denom -> ao16 [s][h*128+d]; denom lives in O[mt][8] at l15==0
  const size_t obase = (size_t)(g * LSEG + tq * 128);
#pragma unroll
  for (int mt = 0; mt < 2; mt++)
#pragma unroll
    for (int rg = 0; rg < 4; rg++) {
      float inv = 1.f / bcast16(O[mt][8][rg]);
#pragma unroll
      for (int d8 = 0; d8 < 8; d8++)
        ao16[(obase + w * 32 + mt * 16 + l4 * 4 + rg) * 2048 + h * HD + d8 * 16 + l15] =
            (_Float16)(O[mt][d8][rg] * inv);
    }
}

extern "C" void kernel_launch(void* const* d_in, const int* in_sizes, int n_in,
                              void* d_out, int out_size, void* d_ws, size_t ws_size,
                              hipStream_t stream) {
  const float* hid  = (const float*)d_in[0];
  // d_in[1] = cu_seqlens: static equal segments, unused
  const float* cosp = (const float*)d_in[2];
  const float* sinp = (const float*)d_in[3];
  const float* wq   = (const float*)d_in[4];
  const float* wk   = (const float*)d_in[5];
  const float* wv   = (const float*)d_in[6];
  const float* wo   = (const float*)d_in[7];
  const float* qnw  = (const float*)d_in[8];
  const float* knw  = (const float*)d_in[9];
  float* out = (float*)d_out;

  _Float16* hid16 = (_Float16*)d_ws;
  _Float16* wqkv  = hid16 + 8388608;
  _Float16* wo16  = wqkv + 4194304;
  _Float16* q16   = wo16 + 2097152;
  _Float16* k16   = q16 + 16777216;
  _Float16* v16T  = k16 + 8388608;
  _Float16* ao16  = v16T + 8388608;

  convert_kernel<<<dim3(1024), dim3(256), 0, stream>>>(hid, wq, wk, wv, wo, hid16, wqkv, wo16);
  gemm_kernel<1><<<dim3(32, 64), dim3(256), 0, stream>>>(hid16, wqkv, nullptr, 1024, 4096,
                                                         cosp, sinp, qnw, knw, q16, k16, v16T);
  attn_kernel<<<dim3(1024), dim3(256), 0, stream>>>(q16, k16, v16T, ao16);
  gemm_kernel<0><<<dim3(8, 64), dim3(256), 0, stream>>>(ao16, wo16, out, 2048, 1024,
                                                        nullptr, nullptr, nullptr, nullptr,
                                                        nullptr, nullptr, nullptr);
}

// Round 10
// 366.227 us; speedup vs baseline: 1.2015x; 1.0639x over previous
//
#include <hip/hip_runtime.h>

// Problem constants (fixed by setup_inputs)
#define S_LEN 8192
#define HID   1024
#define NH    16
#define NKV   8
#define HD    128
#define LSEG  1024
// ws layout (halves): hid16[8388608] | wqkv[4194304] | wo16[2097152] |
//                     q16[16777216] | k16[8388608] | v16T[8388608] | ao16[16777216]

typedef float  f4  __attribute__((ext_vector_type(4)));
typedef _Float16 h4 __attribute__((ext_vector_type(4)));
typedef _Float16 h8 __attribute__((ext_vector_type(8)));

__device__ __forceinline__ void gl_lds16(const void* g, void* l) {
  __builtin_amdgcn_global_load_lds((const __attribute__((address_space(1))) void*)g,
                                   (__attribute__((address_space(3))) void*)l, 16, 0, 0);
}

__device__ __forceinline__ h8 ld8u(const _Float16* p) {  // 8B-aligned LDS load
  h4 a = *(const h4*)p;
  h4 b = *(const h4*)(p + 4);
  return __builtin_shufflevector(a, b, 0, 1, 2, 3, 4, 5, 6, 7);
}

// ---- pure-VALU 16-lane reductions via DPP (no ds_swizzle) ----
template <int CTRL>
__device__ __forceinline__ float dppf(float v) {
  return __builtin_bit_cast(float,
      __builtin_amdgcn_mov_dpp(__builtin_bit_cast(int, v), CTRL, 0xF, 0xF, true));
}
__device__ __forceinline__ float red16_max(float x) {
  x = fmaxf(x, dppf<0xB1>(x));   // quad_perm [1,0,3,2]  (xor 1)
  x = fmaxf(x, dppf<0x4E>(x));   // quad_perm [2,3,0,1]  (xor 2)
  x = fmaxf(x, dppf<0x141>(x));  // row_half_mirror      (combine quads in 8)
  x = fmaxf(x, dppf<0x140>(x));  // row_mirror           (combine 8s in 16)
  return x;
}
__device__ __forceinline__ float red16_sum(float x) {
  x += dppf<0xB1>(x);
  x += dppf<0x4E>(x);
  x += dppf<0x141>(x);
  x += dppf<0x140>(x);
  return x;
}
// broadcast from lane (l & 0x10) -- BitMode and=0x10, or=0, xor=0
__device__ __forceinline__ float bcast16(float v) {
  return __builtin_bit_cast(float,
      __builtin_amdgcn_ds_swizzle(__builtin_bit_cast(int, v), 0x0010));
}

// ---------------- fp32 -> fp16 conversion (all operands) ----------------
__global__ void convert_kernel(const float* __restrict__ hid, const float* __restrict__ wq,
                               const float* __restrict__ wk, const float* __restrict__ wv,
                               const float* __restrict__ wo,
                               _Float16* __restrict__ hid16, _Float16* __restrict__ wqkv,
                               _Float16* __restrict__ wo16) {
  const int total4 = 3670016;  // 14,680,064 / 4
  for (int i = blockIdx.x * blockDim.x + threadIdx.x; i < total4; i += gridDim.x * blockDim.x) {
    int i4 = i * 4;
    const float* src; _Float16* dst;
    if      (i4 <  8388608) { src = hid + i4;              dst = hid16 + i4; }
    else if (i4 < 10485760) { src = wq + (i4 -  8388608);  dst = wqkv + (i4 - 8388608); }
    else if (i4 < 11534336) { src = wk + (i4 - 10485760);  dst = wqkv + 2097152 + (i4 - 10485760); }
    else if (i4 < 12582912) { src = wv + (i4 - 11534336);  dst = wqkv + 3145728 + (i4 - 11534336); }
    else                    { src = wo + (i4 - 12582912);  dst = wo16 + (i4 - 12582912); }
    f4 x = *(const f4*)src;
    h4 y; y[0]=(_Float16)x[0]; y[1]=(_Float16)x[1]; y[2]=(_Float16)x[2]; y[3]=(_Float16)x[3];
    *(h4*)dst = y;
  }
}

// ---------------- 128x128-tile f16 MFMA GEMM (C = A @ B^T), BK=64 ----------------
// XCD-chunked block swizzle (T1): XCD k gets a contiguous range of tile ids so
// its A-panels stay L2-resident.
template <int FUSED>
__global__ __launch_bounds__(256, 3)
void gemm_kernel(const _Float16* __restrict__ A, const _Float16* __restrict__ B,
                 float* __restrict__ Cout, int K, int N,
                 const float* __restrict__ cosp, const float* __restrict__ sinp,
                 const float* __restrict__ qnw, const float* __restrict__ knw,
                 _Float16* __restrict__ q16, _Float16* __restrict__ k16,
                 _Float16* __restrict__ v16T) {
  __shared__ __align__(16) char smem[32768];  // As0 8K | As1 8K | Bs0 8K | Bs1 8K

  constexpr int GX  = FUSED ? 32 : 8;       // gridDim.x (compile-time)
  constexpr int NWG = FUSED ? 2048 : 512;   // total blocks; % 8 == 0 -> bijective
  const int lin = blockIdx.y * GX + blockIdx.x;            // HW dispatch order (x-fast)
  const int swz = (lin & 7) * (NWG >> 3) + (lin >> 3);     // XCD k -> contiguous chunk
  const int bx = swz & (GX - 1), by = swz / GX;

  const int tid = threadIdx.x, w = tid >> 6, ln = tid & 63;
  const int l15 = ln & 15, l4 = ln >> 4;
  const int m0 = by * 128, n0 = bx * 128;
  const int sg_row = ln >> 2, sg_cho = (ln & 3) * 8;

  f4 acc[2][8] = {};

  for (int k0 = 0; k0 < K; k0 += 64) {
    __syncthreads();
#pragma unroll
    for (int r = 0; r < 2; r++) {
      int ch = r * 4 + w;  // wave-uniform 1KB chunk id (0..7)
#pragma unroll
      for (int u = 0; u < 2; u++) {
        gl_lds16(A + (size_t)(m0 + ch * 16 + sg_row) * K + k0 + u * 32 + sg_cho,
                 smem + u * 8192 + ch * 1024);
        gl_lds16(B + (size_t)(n0 + ch * 16 + sg_row) * K + k0 + u * 32 + sg_cho,
                 smem + 16384 + u * 8192 + ch * 1024);
      }
    }
    __syncthreads();
#pragma unroll
    for (int u = 0; u < 2; u++) {
      const _Float16* As = (const _Float16*)(smem + u * 8192);
      const _Float16* Bs = (const _Float16*)(smem + 16384 + u * 8192);
      h8 af[2], bf[8];
#pragma unroll
      for (int mt = 0; mt < 2; mt++) af[mt] = *(const h8*)(As + (w * 32 + mt * 16 + l15) * 32 + l4 * 8);
#pragma unroll
      for (int nt = 0; nt < 8; nt++) bf[nt] = *(const h8*)(Bs + (nt * 16 + l15) * 32 + l4 * 8);
#pragma unroll
      for (int mt = 0; mt < 2; mt++)
#pragma unroll
        for (int nt = 0; nt < 8; nt++)
          acc[mt][nt] = __builtin_amdgcn_mfma_f32_16x16x32_f16(af[mt], bf[nt], acc[mt][nt], 0, 0, 0);
    }
  }

  if (!FUSED) {
    // plain fp32 epilogue (output projection)
#pragma unroll
    for (int mt = 0; mt < 2; mt++)
#pragma unroll
      for (int rg = 0; rg < 4; rg++) {
        int row = m0 + w * 32 + mt * 16 + l4 * 4 + rg;
#pragma unroll
        for (int nt = 0; nt < 8; nt++)
          Cout[(size_t)row * N + n0 + nt * 16 + l15] = acc[mt][nt][rg];
      }
    return;
  } else {
    // fused RMSNorm + multimodal RoPE epilogue -> q16/k16 ([h][s][d]) and v16T ([hkv][d][s])
    const int head = bx;  // 0..15 q, 16..23 k, 24..31 v
    if (head < 24) {
      const float* nw = (head < 16) ? qnw : knw;
      // q: fold D^-0.5 * log2(e) (attn softmax runs in exp2 domain)
      const float hs = (head < 16) ? 0.12751734f : 1.0f;
      _Float16* base = (head < 16) ? q16 + (size_t)head * S_LEN * HD
                                   : k16 + (size_t)(head - 16) * S_LEN * HD;
      float nwv[8];
#pragma unroll
      for (int nt = 0; nt < 8; nt++) nwv[nt] = nw[nt * 16 + l15];
#pragma unroll
      for (int mt = 0; mt < 2; mt++)
#pragma unroll
        for (int rg = 0; rg < 4; rg++) {
          const int row = m0 + w * 32 + mt * 16 + l4 * 4 + rg;  // global s
          float ss = 0.f;
#pragma unroll
          for (int nt = 0; nt < 8; nt++) ss += acc[mt][nt][rg] * acc[mt][nt][rg];
          ss = red16_sum(ss);
          const float sc = rsqrtf(ss * 0.0078125f + 1e-6f);
#pragma unroll
          for (int nt = 0; nt < 8; nt++) {
            const int c = nt * 16 + l15;
            const int str = (nt >= 4) ? 1048576 : 0;  // RoPE stream per half-dim
            float x  = acc[mt][nt][rg] * sc * nwv[nt];
            float xp = acc[mt][nt ^ 4][rg] * sc * nwv[nt ^ 4];
            float ce = cosp[str + row * HD + c];
            float se = sinp[str + row * HD + c];
            float rot = (nt >= 4) ? xp : -xp;
            base[(size_t)row * HD + c] = (_Float16)((x * ce + rot * se) * hs);
          }
        }
    } else {
      // V: h4 stores -- rg=0..3 are 4 consecutive s-rows for fixed d -> 8B contiguous
      _Float16* vb = v16T + (size_t)(head - 24) * S_LEN * HD;  // [d][s]
#pragma unroll
      for (int mt = 0; mt < 2; mt++)
#pragma unroll
        for (int nt = 0; nt < 8; nt++) {
          h4 hv;
#pragma unroll
          for (int rg = 0; rg < 4; rg++) hv[rg] = (_Float16)acc[mt][nt][rg];
          *(h4*)&vb[(size_t)(nt * 16 + l15) * S_LEN + m0 + w * 32 + mt * 16 + l4 * 4] = hv;
        }
    }
  }
}

// ---------------- flash attention, R15: 1 barrier/iter (R7 structure, R14 layouts) ----------------
// R14 anchor (128.7us). Remaining stall: 3 barriers/iter lock-step.
// R7's 1-barrier pipeline, rebuilt with PROVEN padded-stride layouts (no XOR
// swizzle -- R13 showed that costs 16M conflicts):
//  - K double-buffered [2][64][132]. Kb[nxt] is dead between iters -> K restage
//    (global-spread, R14 coords) needs no barrier.
//  - P lives in Vb[nxt] ([128][68], same stride as V). Wave w writes/reads only
//    P rows [32w,32w+32); V-restage is wave-local over exactly those rows
//    (lane -> row 32w+(ln>>1)), placed after own PV -> tile j+1's V overwrites
//    this wave's own dead P. No cross-wave hazard; same-wave RAW via lgkmcnt.
//  - Q in registers (32 VGPR). Budget: ~200 live at (256,2) cap 256 -> no spill
//    (R6/R7 spilled at cap 168).
//  - Denominator ones-row -> in-register B-fragment (l15==0 ? 1 : 0); epilogue
//    identical to R14 (bcast16). Vt sheds its 16 extra rows.
// LDS: 2*16896 + 2*17408 = 68608 B (same as R14) -> 2 blocks/CU.
__global__ __launch_bounds__(256, 2)
void attn_kernel(const _Float16* __restrict__ q16, const _Float16* __restrict__ k16,
                 const _Float16* __restrict__ vT, _Float16* __restrict__ ao16) {
  const int bid = blockIdx.x;
  const int xcd = bid & 7, slot = bid >> 3;   // 8 XCDs x 128 slots (1024 % 8 == 0)
  const int grp = xcd * 8 + (slot >> 4);      // 0..63 = (g, hkv) group, 8 groups/XCD
  const int mem = slot & 15;                  // 16 members share this group's K/V (512KB)
  const int g = grp >> 3, hkv = grp & 7;
  const int tq = mem & 7, h = hkv * 2 + (mem >> 3);

  const int tid = threadIdx.x, w = tid >> 6, ln = tid & 63;
  const int l15 = ln & 15, l4 = ln >> 4;

  __shared__ _Float16 Kb[2][64 * 132];  // K [l][d] stride 132, 16896 B each
  __shared__ _Float16 Vb[2][128 * 68];  // V [d][l(64)] stride 68, 17408 B each;
                                        // P [q][l] stride 68 overlays Vb[nxt] (own q rows)

  // ---- Q tile: per-wave A-fragments straight into registers ----
  const _Float16* qsrc = q16 + ((size_t)h * S_LEN + g * LSEG + tq * 128 + w * 32) * HD;
  h8 qf[2][4];
#pragma unroll
  for (int mt = 0; mt < 2; mt++)
#pragma unroll
    for (int kk = 0; kk < 4; kk++)
      qf[mt][kk] = *(const h8*)(qsrc + (size_t)(mt * 16 + l15) * HD + kk * 32 + l4 * 8);

  // ones B-fragment: col 0 = ones -> denominator lands in D col 0 (same layout as R14)
  h8 onesB;
  {
    _Float16 ov = (l15 == 0) ? (_Float16)1.0f : (_Float16)0.0f;
#pragma unroll
    for (int jj = 0; jj < 8; jj++) onesB[jj] = ov;
  }

  f4 O[2][9] = {};   // [mt][0..7]=output tiles, [mt][8]=denominator tile
  float mr[2][4];
#pragma unroll
  for (int mt = 0; mt < 2; mt++)
#pragma unroll
    for (int rg = 0; rg < 4; rg++) mr[mt][rg] = -1e30f;

  const size_t kbase = ((size_t)hkv * S_LEN + g * LSEG) * HD;
  const size_t vbase = (size_t)hkv * S_LEN * HD + (size_t)g * LSEG;

  // global-spread staging coords (K always; V initial tile only)
  const int krow = tid >> 4, ko = tid & 15;   // + 16*i rows
  const int vd   = tid >> 3, vo = tid & 7;    // + 32*i d-rows
  // wave-local V restage coords: rows [32w, 32w+32) == this wave's P rows
  const int vrow = w * 32 + (ln >> 1), vcol = (ln & 1) * 32;  // + c*8 halves

  // ---- stage tile 0 into Kb[0]/Vb[0] ----
  uint4 kr[4], vr[4];
#pragma unroll
  for (int i = 0; i < 4; i++) {
    kr[i] = *(const uint4*)(k16 + kbase + (size_t)(krow + 16 * i) * HD + ko * 8);
    vr[i] = *(const uint4*)(vT + vbase + (size_t)(vd + 32 * i) * S_LEN + vo * 8);
  }
#pragma unroll
  for (int i = 0; i < 4; i++) {
    int row = krow + 16 * i;
    *(uint2*)&Kb[0][row * 132 + ko * 8]     = make_uint2(kr[i].x, kr[i].y);
    *(uint2*)&Kb[0][row * 132 + ko * 8 + 4] = make_uint2(kr[i].z, kr[i].w);
    int d = vd + 32 * i;
    *(uint2*)&Vb[0][d * 68 + vo * 8]     = make_uint2(vr[i].x, vr[i].y);
    *(uint2*)&Vb[0][d * 68 + vo * 8 + 4] = make_uint2(vr[i].z, vr[i].w);
  }

  for (int j = 0; j < 16; j++) {
    __syncthreads();  // the ONLY barrier: all restages of tile j visible
    const int cur = j & 1, nxt = cur ^ 1;
    const _Float16* Kc = Kb[cur];
    const _Float16* Vc = Vb[cur];
    _Float16* Pb = Vb[nxt];   // P buffer (own rows); becomes V[j+1] at restage
    _Float16* Kn = Kb[nxt];   // dead buffer -> free restage target

    // ---- issue prefetch loads for tile j+1 ----
    if (j < 15) {
      const int jn = j + 1;
#pragma unroll
      for (int i = 0; i < 4; i++)
        kr[i] = *(const uint4*)(k16 + kbase + (size_t)(jn * 64 + krow + 16 * i) * HD + ko * 8);
#pragma unroll
      for (int c = 0; c < 4; c++)
        vr[c] = *(const uint4*)(vT + vbase + (size_t)vrow * S_LEN + jn * 64 + vcol + c * 8);
    }

    // S = Q K^T  (A from regs, B from Kb[cur])
    f4 s[2][4] = {};
    __builtin_amdgcn_s_setprio(1);
#pragma unroll
    for (int kk = 0; kk < 4; kk++) {
#pragma unroll
      for (int nt = 0; nt < 4; nt++) {
        h8 b = ld8u(Kc + (nt * 16 + l15) * 132 + kk * 32 + l4 * 8);
        s[0][nt] = __builtin_amdgcn_mfma_f32_16x16x32_f16(qf[0][kk], b, s[0][nt], 0, 0, 0);
        s[1][nt] = __builtin_amdgcn_mfma_f32_16x16x32_f16(qf[1][kk], b, s[1][nt], 0, 0, 0);
      }
    }
    __builtin_amdgcn_s_setprio(0);

    // ---- chain-free softmax: detection-only defer-max (T13) ----
    bool nd = false;
#pragma unroll
    for (int mt = 0; mt < 2; mt++)
#pragma unroll
      for (int rg = 0; rg < 4; rg++) {
        float thr = mr[mt][rg] + 8.f;
        nd = nd || (s[mt][0][rg] > thr) || (s[mt][1][rg] > thr) ||
                   (s[mt][2][rg] > thr) || (s[mt][3][rg] > thr);
      }
    const bool needr = __any((int)nd) != 0;  // wave-uniform, rare
    float al[2][4];
    if (needr) {
#pragma unroll
      for (int mt = 0; mt < 2; mt++)
#pragma unroll
        for (int rg = 0; rg < 4; rg++) {
          float m = fmaxf(fmaxf(s[mt][0][rg], s[mt][1][rg]), fmaxf(s[mt][2][rg], s[mt][3][rg]));
          m = red16_max(m);
          float mnew = fmaxf(mr[mt][rg], m);
          al[mt][rg] = exp2f(mr[mt][rg] - mnew);
          mr[mt][rg] = mnew;
        }
    }
    // P = exp2(S - mr); denominator comes from the onesB MFMA
#pragma unroll
    for (int mt = 0; mt < 2; mt++)
#pragma unroll
      for (int rg = 0; rg < 4; rg++)
#pragma unroll
        for (int nt = 0; nt < 4; nt++)
          s[mt][nt][rg] = exp2f(s[mt][nt][rg] - mr[mt][rg]);

    // ---- P -> Vb[nxt] own rows (wave-local; no barrier) ----
#pragma unroll
    for (int mt = 0; mt < 2; mt++)
#pragma unroll
      for (int nt = 0; nt < 4; nt++)
#pragma unroll
        for (int rg = 0; rg < 4; rg++)
          Pb[(w * 32 + mt * 16 + l4 * 4 + rg) * 68 + nt * 16 + l15] = (_Float16)s[mt][nt][rg];
    // rescale O (incl. denominator tile) while P-write settles; usually skipped
    if (needr) {
#pragma unroll
      for (int mt = 0; mt < 2; mt++)
#pragma unroll
        for (int d8 = 0; d8 < 9; d8++)
#pragma unroll
          for (int rg = 0; rg < 4; rg++) O[mt][d8][rg] *= al[mt][rg];
    }

    // O += P @ V   (A = own P rows from Vb[nxt], B = Vb[cur]; onesB = denominator)
    __builtin_amdgcn_s_setprio(1);
#pragma unroll
    for (int kk = 0; kk < 2; kk++) {
      h8 a0 = ld8u(Pb + (w * 32 + l15) * 68 + kk * 32 + l4 * 8);
      h8 a1 = ld8u(Pb + (w * 32 + 16 + l15) * 68 + kk * 32 + l4 * 8);
#pragma unroll
      for (int d8 = 0; d8 < 8; d8++) {
        h8 b = ld8u(Vc + (d8 * 16 + l15) * 68 + kk * 32 + l4 * 8);
        O[0][d8] = __builtin_amdgcn_mfma_f32_16x16x32_f16(a0, b, O[0][d8], 0, 0, 0);
        O[1][d8] = __builtin_amdgcn_mfma_f32_16x16x32_f16(a1, b, O[1][d8], 0, 0, 0);
      }
      O[0][8] = __builtin_amdgcn_mfma_f32_16x16x32_f16(a0, onesB, O[0][8], 0, 0, 0);
      O[1][8] = __builtin_amdgcn_mfma_f32_16x16x32_f16(a1, onesB, O[1][8], 0, 0, 0);
    }
    __builtin_amdgcn_s_setprio(0);

    // ---- restage tile j+1 (no barrier) ----
    if (j < 15) {
      // K: global-spread into the dead Kb[nxt]
#pragma unroll
      for (int i = 0; i < 4; i++) {
        int row = krow + 16 * i;
        *(uint2*)&Kn[row * 132 + ko * 8]     = make_uint2(kr[i].x, kr[i].y);
        *(uint2*)&Kn[row * 132 + ko * 8 + 4] = make_uint2(kr[i].z, kr[i].w);
      }
      // V: wave-local rows [32w,32w+32) -- overwrites ONLY this wave's dead P
#pragma unroll
      for (int c = 0; c < 4; c++) {
        *(uint2*)&Pb[vrow * 68 + vcol + c * 8]     = make_uint2(vr[c].x, vr[c].y);
        *(uint2*)&Pb[vrow * 68 + vcol + c * 8 + 4] = make_uint2(vr[c].z, vr[c].w);
      }
    }
  }

  // epilogue: O / denom -> ao16 [s][h*128+d]; denom in O[mt][8] at l15==0 (bcast16)
  const size_t obase = (size_t)(g * LSEG + tq * 128);
#pragma unroll
  for (int mt = 0; mt < 2; mt++)
#pragma unroll
    for (int rg = 0; rg < 4; rg++) {
      float inv = 1.f / bcast16(O[mt][8][rg]);
#pragma unroll
      for (int d8 = 0; d8 < 8; d8++)
        ao16[(obase + w * 32 + mt * 16 + l4 * 4 + rg) * 2048 + h * HD + d8 * 16 + l15] =
            (_Float16)(O[mt][d8][rg] * inv);
    }
}

extern "C" void kernel_launch(void* const* d_in, const int* in_sizes, int n_in,
                              void* d_out, int out_size, void* d_ws, size_t ws_size,
                              hipStream_t stream) {
  const float* hid  = (const float*)d_in[0];
  // d_in[1] = cu_seqlens: static equal segments, unused
  const float* cosp = (const float*)d_in[2];
  const float* sinp = (const float*)d_in[3];
  const float* wq   = (const float*)d_in[4];
  const float* wk   = (const float*)d_in[5];
  const float* wv   = (const float*)d_in[6];
  const float* wo   = (const float*)d_in[7];
  const float* qnw  = (const float*)d_in[8];
  const float* knw  = (const float*)d_in[9];
  float* out = (float*)d_out;

  _Float16* hid16 = (_Float16*)d_ws;
  _Float16* wqkv  = hid16 + 8388608;
  _Float16* wo16  = wqkv + 4194304;
  _Float16* q16   = wo16 + 2097152;
  _Float16* k16   = q16 + 16777216;
  _Float16* v16T  = k16 + 8388608;
  _Float16* ao16  = v16T + 8388608;

  convert_kernel<<<dim3(1024), dim3(256), 0, stream>>>(hid, wq, wk, wv, wo, hid16, wqkv, wo16);
  gemm_kernel<1><<<dim3(32, 64), dim3(256), 0, stream>>>(hid16, wqkv, nullptr, 1024, 4096,
                                                         cosp, sinp, qnw, knw, q16, k16, v16T);
  attn_kernel<<<dim3(1024), dim3(256), 0, stream>>>(q16, k16, v16T, ao16);
  gemm_kernel<0><<<dim3(8, 64), dim3(256), 0, stream>>>(ao16, wo16, out, 2048, 1024,
                                                        nullptr, nullptr, nullptr, nullptr,
                                                        nullptr, nullptr, nullptr);
}